// Round 10
// baseline (20492.918 us; speedup 1.0000x reference)
//
#include <hip/hip_runtime.h>

// Problem constants
#define IN_DIM 128
#define HID    512
#define BATCH  256
#define SEQT   512
#define G4H    2048
#define K0     640       // IN_DIM + HID (layer0 concat K)
#define K1     1024      // HID + HID   (layer1 concat K)
#define NC0    20        // K0/32
#define NC1    32        // K1/32
#define GR     16        // batch rows per group
#define ROWB   2048      // bytes per A row (1024 bf16 cols)

typedef __attribute__((ext_vector_type(8))) short bf16x8;
typedef __attribute__((ext_vector_type(4))) float f32x4;

#define MFMA16 __builtin_amdgcn_mfma_f32_16x16x32_bf16
// glf layout [row 16][gate 4][col 64 + 2 pad]
#define GL(r, g, c) ((r) * 264 + (g) * 66 + (c))

__device__ __forceinline__ unsigned short f2bf(float f) {  // RNE float->bf16
  unsigned u = __float_as_uint(f);
  u += 0x7fffu + ((u >> 16) & 1u);
  return (unsigned short)(u >> 16);
}
__device__ __forceinline__ float bf2f(unsigned short s) {
  return __uint_as_float(((unsigned)s) << 16);
}
__device__ __forceinline__ float sigm(float x) { return 1.0f / (1.0f + __expf(-x)); }
__device__ __forceinline__ float tanh_f(float x) {
  float xc = fminf(fmaxf(x, -15.0f), 15.0f);
  float e = __expf(2.0f * xc);
  return (e - 1.0f) / (e + 1.0f);
}

__device__ __forceinline__ unsigned ald(const unsigned* p) {
  return __hip_atomic_load(p, __ATOMIC_RELAXED, __HIP_MEMORY_SCOPE_AGENT);
}

// ---------------------------------------------------------------------------
// Prep: packed hi/lo bf16 weight tiles + bias sums (layout unchanged from R8).
// Tile t = slice16*4+gate; within tile: [kchunk][lane(col=l&15, ko=(l>>4)*8)][8].
// ---------------------------------------------------------------------------
__global__ void conv_weights(const float* __restrict__ Wih0, const float* __restrict__ Whh0,
                             const float* __restrict__ Wih1, const float* __restrict__ Whh1,
                             const float* __restrict__ bih0, const float* __restrict__ bhh0,
                             const float* __restrict__ bih1, const float* __restrict__ bhh1,
                             short* __restrict__ W0h, short* __restrict__ W0l,
                             short* __restrict__ W1h, short* __restrict__ W1l,
                             float* __restrict__ bsum0, float* __restrict__ bsum1) {
  int idx = blockIdx.x * blockDim.x + threadIdx.x;
  const int N0 = G4H * K0, N1 = G4H * K1;
  if (idx < N0) {
    int tile = idx / (K0 * 16), rem = idx % (K0 * 16);
    int kcg = rem >> 9, l = (rem >> 3) & 63, j = rem & 7;
    int slice = tile >> 2, g = tile & 3;
    int c = l & 15, k = kcg * 32 + ((l >> 4) << 3) + j;
    int n = g * HID + slice * 16 + c;
    float w = (k < IN_DIM) ? Wih0[n * IN_DIM + k] : Whh0[n * HID + (k - IN_DIM)];
    unsigned short hi = f2bf(w);
    W0h[idx] = (short)hi;
    W0l[idx] = (short)f2bf(w - bf2f(hi));
  } else if (idx < N0 + N1) {
    int d = idx - N0;
    int tile = d / (K1 * 16), rem = d % (K1 * 16);
    int kcg = rem >> 9, l = (rem >> 3) & 63, j = rem & 7;
    int slice = tile >> 2, g = tile & 3;
    int c = l & 15, k = kcg * 32 + ((l >> 4) << 3) + j;
    int n = g * HID + slice * 16 + c;
    float w = (k < HID) ? Wih1[n * HID + k] : Whh1[n * HID + (k - HID)];
    unsigned short hi = f2bf(w);
    W1h[d] = (short)hi;
    W1l[d] = (short)f2bf(w - bf2f(hi));
  } else if (idx < N0 + N1 + G4H) {
    int n = idx - (N0 + N1);
    bsum0[n] = bih0[n] + bhh0[n];
  } else if (idx < N0 + N1 + 2 * G4H) {
    int n = idx - (N0 + N1 + G4H);
    bsum1[n] = bih1[n] + bhh1[n];
  }
}

// ---------------------------------------------------------------------------
// Staging: packed h (dword = hi|lo<<16) -> swizzled hi/lo LDS planes.
// A group's h block = [16 rows][512 dwords] = 32KB CONTIGUOUS. Thread tid takes
// 16B chunk c: lane-contiguous -> each wave instruction = 1KB contiguous
// (8 full 128B lines, zero request amplification).
// ---------------------------------------------------------------------------
#define PKH(a, b) ((unsigned)((a) & 0xffffu) | (((b) & 0xffffu) << 16))
#define PKL(a, b) (((a) >> 16) | ((b) & 0xffff0000u))

__device__ __forceinline__ void unpack_chunk(char* AhiB, char* AloB, int colOff,
                                             int c, const uint4& v) {
  const int row  = c >> 7;              // 128 chunks (512 dwords) per row
  const int colb = (c & 127) * 4;       // first col of this chunk
  const int rx   = (row & 7) << 4;
  const int byte0 = (colOff + colb) * 2;
  uint2 hd = {PKH(v.x, v.y), PKH(v.z, v.w)};
  uint2 ld = {PKL(v.x, v.y), PKL(v.z, v.w)};
  *(uint2*)(AhiB + row * ROWB + (byte0 ^ rx)) = hd;
  *(uint2*)(AloB + row * ROWB + (byte0 ^ rx)) = ld;
}

// L0: h0p -> cols [128,640). 2048 chunks, 2 per thread.
__device__ __forceinline__ void stage_L0(char* AhiB, char* AloB,
                                         const unsigned* __restrict__ h0p,
                                         int b0, int tid) {
  const unsigned* pb = h0p + (size_t)b0 * HID;
  const unsigned* a0 = pb + tid * 4;
  const unsigned* a1 = a0 + 4096;
  uint4 v0, v1;
  asm volatile(
      "global_load_dwordx4 %0, %2, off sc0 sc1\n\t"
      "global_load_dwordx4 %1, %3, off sc0 sc1\n\t"
      "s_waitcnt vmcnt(0)"
      : "=&v"(v0), "=&v"(v1)
      : "v"(a0), "v"(a1)
      : "memory");
  unpack_chunk(AhiB, AloB, IN_DIM, tid, v0);
  unpack_chunk(AhiB, AloB, IN_DIM, tid + 1024, v1);
}

// L1: h0p -> cols [0,512), h2p -> cols [512,1024). 4 chunks per thread.
__device__ __forceinline__ void stage_L1(char* AhiB, char* AloB,
                                         const unsigned* __restrict__ h0p,
                                         const unsigned* __restrict__ h2p,
                                         int b0, int tid) {
  const unsigned* pa = h0p + (size_t)b0 * HID;
  const unsigned* pb = h2p + (size_t)b0 * HID;
  const unsigned* a0 = pa + tid * 4;
  const unsigned* a1 = a0 + 4096;
  const unsigned* b0p = pb + tid * 4;
  const unsigned* b1p = b0p + 4096;
  uint4 v0, v1, w0, w1;
  asm volatile(
      "global_load_dwordx4 %0, %4, off sc0 sc1\n\t"
      "global_load_dwordx4 %1, %5, off sc0 sc1\n\t"
      "global_load_dwordx4 %2, %6, off sc0 sc1\n\t"
      "global_load_dwordx4 %3, %7, off sc0 sc1\n\t"
      "s_waitcnt vmcnt(0)"
      : "=&v"(v0), "=&v"(v1), "=&v"(w0), "=&v"(w1)
      : "v"(a0), "v"(a1), "v"(b0p), "v"(b1p)
      : "memory");
  unpack_chunk(AhiB, AloB, 0, tid, v0);
  unpack_chunk(AhiB, AloB, 0, tid + 1024, v1);
  unpack_chunk(AhiB, AloB, HID, tid, w0);
  unpack_chunk(AhiB, AloB, HID, tid + 1024, w1);
}
#undef PKH
#undef PKL

// ---------------------------------------------------------------------------
// Per-wave GEMM: 16 rows x 64 cols (4 N-tiles) over NKC k-chunks.
// Split precision: hi*hi + hi*lo + lo*hi (12 MFMA / chunk).
// ---------------------------------------------------------------------------
template <int NKC>
__device__ __forceinline__ void gemm64(const char* Ah, const char* Al,
                                       const short* __restrict__ Bh0, const short* __restrict__ Bl0,
                                       const short* __restrict__ Bh1, const short* __restrict__ Bl1,
                                       const short* __restrict__ Bh2, const short* __restrict__ Bl2,
                                       const short* __restrict__ Bh3, const short* __restrict__ Bl3,
                                       int lane, int aoff,
                                       f32x4& c0, f32x4& c1, f32x4& c2, f32x4& c3) {
  const int row = lane & 15;
  const int ko  = (lane >> 4) * 8;
  const int rx  = (row & 7) << 4;
  const char* pAh = Ah + row * ROWB;
  const char* pAl = Al + row * ROWB;
#pragma unroll
  for (int kc = 0; kc < NKC; ++kc) {
    const int off = ((aoff + kc * 32 + ko) * 2) ^ rx;
    bf16x8 ah = *(const bf16x8*)(pAh + off);
    bf16x8 al = *(const bf16x8*)(pAl + off);
    const int bo = kc * 512 + lane * 8;
    bf16x8 bh0 = *(const bf16x8*)(Bh0 + bo);
    bf16x8 bl0 = *(const bf16x8*)(Bl0 + bo);
    bf16x8 bh1 = *(const bf16x8*)(Bh1 + bo);
    bf16x8 bl1 = *(const bf16x8*)(Bl1 + bo);
    bf16x8 bh2 = *(const bf16x8*)(Bh2 + bo);
    bf16x8 bl2 = *(const bf16x8*)(Bl2 + bo);
    bf16x8 bh3 = *(const bf16x8*)(Bh3 + bo);
    bf16x8 bl3 = *(const bf16x8*)(Bl3 + bo);
    c0 = MFMA16(ah, bh0, c0, 0, 0, 0);
    c0 = MFMA16(ah, bl0, c0, 0, 0, 0);
    c0 = MFMA16(al, bh0, c0, 0, 0, 0);
    c1 = MFMA16(ah, bh1, c1, 0, 0, 0);
    c1 = MFMA16(ah, bl1, c1, 0, 0, 0);
    c1 = MFMA16(al, bh1, c1, 0, 0, 0);
    c2 = MFMA16(ah, bh2, c2, 0, 0, 0);
    c2 = MFMA16(ah, bl2, c2, 0, 0, 0);
    c2 = MFMA16(al, bh2, c2, 0, 0, 0);
    c3 = MFMA16(ah, bh3, c3, 0, 0, 0);
    c3 = MFMA16(ah, bl3, c3, 0, 0, 0);
    c3 = MFMA16(al, bh3, c3, 0, 0, 0);
  }
}

__device__ __forceinline__ void finq(float* glf, int g, int lane,
                                     const f32x4& c0, const f32x4& c1,
                                     const f32x4& c2, const f32x4& c3) {
  // C/D layout: col = lane&15, row = (lane>>4)*4 + reg  [measured m89]
  const int col = lane & 15;
  const int r0  = (lane >> 4) * 4;
#pragma unroll
  for (int r = 0; r < 4; ++r) {
    atomicAdd(glf + GL(r0 + r, g, col), c0[r]);        // ds_add_f32
    atomicAdd(glf + GL(r0 + r, g, 16 + col), c1[r]);
    atomicAdd(glf + GL(r0 + r, g, 32 + col), c2[r]);
    atomicAdd(glf + GL(r0 + r, g, 48 + col), c3[r]);
  }
}

// ---------------------------------------------------------------------------
// Flag-array group barrier (16 WGs): each WG stores step number to its OWN
// dword; wave 0 polls all 16 flags in one vector load round.
// ---------------------------------------------------------------------------
__device__ __forceinline__ void group_barrier(unsigned* flags, unsigned target,
                                              int tid, int wid) {
  asm volatile("s_waitcnt vmcnt(0)" ::: "memory");
  __syncthreads();
  if (tid < 64) {
    if (tid == 0)
      __hip_atomic_store(flags + wid, target, __ATOMIC_RELAXED,
                         __HIP_MEMORY_SCOPE_AGENT);
    const int i = tid & 15;
    while (true) {
      unsigned v = ald(flags + i);
      if (__all((int)(v >= target))) break;
      __builtin_amdgcn_s_sleep(1);
    }
  }
  __syncthreads();
}

// ---------------------------------------------------------------------------
// Persistent fused 2-layer LSTM. 256 WGs x 1024 thr (16 waves, 4/SIMD).
// 16 groups x 16 batch rows. grp = blk>>4; wid = blk&15:
//   wid 0-7  = layer 0 (64 hid cols each; reads x_t + h0p, writes h0c)
//   wid 8-15 = layer 1, one step behind  (reads h0p + h2p, writes h2c)
// Wave w: gate g = w&3, K-quarter kq = w>>2; gate partials via LDS atomicAdd.
// ---------------------------------------------------------------------------
__global__ void __launch_bounds__(1024, 4) lstm_fused(
    const float* __restrict__ x,
    const float* __restrict__ Wfc, const float* __restrict__ bfc,
    const short* __restrict__ W0h, const short* __restrict__ W0l,
    const short* __restrict__ W1h, const short* __restrict__ W1l,
    const float* __restrict__ bsum0, const float* __restrict__ bsum1,
    unsigned* __restrict__ h0s, unsigned* __restrict__ h2s,
    unsigned* __restrict__ counters,
    float* __restrict__ out) {
  const int tid  = threadIdx.x;
  const int wv   = tid >> 6;
  const int lane = tid & 63;
  const int wid  = blockIdx.x & 15;
  const int grp  = blockIdx.x >> 4;
  const int role = wid >> 3;           // 0 = layer0, 1 = layer1
  const int w8   = wid & 7;            // 8 col-slices of 64
  const int hid0 = w8 * 64;
  const int b0   = grp * GR;
  unsigned* flags = counters + grp * 64;

  __shared__ __align__(16) char AhiB[GR * ROWB];   // 32768 B
  __shared__ __align__(16) char AloB[GR * ROWB];   // 32768 B
  __shared__ float glf[16 * 264];                   // 16896 B gate exchange / FC scratch

  const int g  = wv & 3;
  const int kq = wv >> 2;
  // Weight tile pointers: 4 16-col tiles for this wave's 64 cols.
  const short *Bh0, *Bl0, *Bh1, *Bl1, *Bh2, *Bl2, *Bh3, *Bl3;
  int aoff;
  if (role == 0) {
    const size_t base = (size_t)kq * 5 * 512;
#define T0(i) ((size_t)((w8 * 4 + (i)) * 4 + g) * NC0 * 512 + base)
    Bh0 = W0h + T0(0); Bl0 = W0l + T0(0);
    Bh1 = W0h + T0(1); Bl1 = W0l + T0(1);
    Bh2 = W0h + T0(2); Bl2 = W0l + T0(2);
    Bh3 = W0h + T0(3); Bl3 = W0l + T0(3);
#undef T0
    aoff = kq * 160;
  } else {
    const size_t base = (size_t)kq * 8 * 512;
#define T1(i) ((size_t)((w8 * 4 + (i)) * 4 + g) * NC1 * 512 + base)
    Bh0 = W1h + T1(0); Bl0 = W1l + T1(0);
    Bh1 = W1h + T1(1); Bl1 = W1l + T1(1);
    Bh2 = W1h + T1(2); Bl2 = W1l + T1(2);
    Bh3 = W1h + T1(3); Bl3 = W1l + T1(3);
#undef T1
    aoff = kq * 256;
  }

  // Cell state + biases: 1 output/thread (row = tid>>6, col = tid&63)
  float c = 0.f;
  float bs[4];
  {
    const int n = hid0 + (tid & 63);
    const float* bsp = role ? bsum1 : bsum0;
#pragma unroll
    for (int q = 0; q < 4; ++q) bs[q] = bsp[q * HID + n];
  }
  for (int i = tid; i < 16 * 264; i += 1024) glf[i] = 0.f;

  const size_t PL = (size_t)BATCH * HID;

  for (int s = 0; s <= SEQT; ++s) {
    const int cur = s & 1, prv = cur ^ 1;
    unsigned* h0c = h0s + (size_t)cur * PL;
    const unsigned* h0p = h0s + (size_t)prv * PL;
    unsigned* h2c = h2s + (size_t)cur * PL;
    const unsigned* h2p = h2s + (size_t)prv * PL;
    const bool active = role ? (s > 0) : (s < SEQT);

    // ---- stage ----
    if (active) {
      if (role == 0) {
        {  // x_t -> cols [0,128): wave w -> row w, lane l -> 2 floats
          const int row = wv, l = lane;
          const int rx = (row & 7) << 4;
          const float2 xv = *(const float2*)(x + ((size_t)(b0 + row) * SEQT + s) * IN_DIM + l * 2);
          unsigned short h0v = f2bf(xv.x), h1v = f2bf(xv.y);
          unsigned hd = (unsigned)h0v | ((unsigned)h1v << 16);
          unsigned ld = (unsigned)f2bf(xv.x - bf2f(h0v)) |
                        ((unsigned)f2bf(xv.y - bf2f(h1v)) << 16);
          const int byte = (l * 4) ^ rx;
          *(unsigned*)(AhiB + row * ROWB + byte) = hd;
          *(unsigned*)(AloB + row * ROWB + byte) = ld;
        }
        stage_L0(AhiB, AloB, h0p, b0, tid);
      } else {
        stage_L1(AhiB, AloB, h0p, h2p, b0, tid);
      }
    }
    __syncthreads();

    // ---- gemm + gate reduce ----
    if (active) {
      f32x4 c0 = {0.f, 0.f, 0.f, 0.f}, c1 = {0.f, 0.f, 0.f, 0.f};
      f32x4 c2 = {0.f, 0.f, 0.f, 0.f}, c3 = {0.f, 0.f, 0.f, 0.f};
      if (role == 0)
        gemm64<5>(AhiB, AloB, Bh0, Bl0, Bh1, Bl1, Bh2, Bl2, Bh3, Bl3,
                  lane, aoff, c0, c1, c2, c3);
      else
        gemm64<8>(AhiB, AloB, Bh0, Bl0, Bh1, Bl1, Bh2, Bl2, Bh3, Bl3,
                  lane, aoff, c0, c1, c2, c3);
      finq(glf, g, lane, c0, c1, c2, c3);
    }
    __syncthreads();

    // ---- update + coherent h store ----
    if (active) {
      const int row = tid >> 6, col = tid & 63;
      float gi = glf[GL(row, 0, col)] + bs[0];
      float gf = glf[GL(row, 1, col)] + bs[1];
      float gg = glf[GL(row, 2, col)] + bs[2];
      float go = glf[GL(row, 3, col)] + bs[3];
      glf[GL(row, 0, col)] = 0.f; glf[GL(row, 1, col)] = 0.f;
      glf[GL(row, 2, col)] = 0.f; glf[GL(row, 3, col)] = 0.f;
      float i = sigm(gi), f = sigm(gf), gv = tanh_f(gg), o = sigm(go);
      float cc = f * c + i * gv;
      c = cc;
      float h = o * tanh_f(cc);
      unsigned short hh = f2bf(h);
      unsigned short hl = f2bf(h - bf2f(hh));
      unsigned pk = (unsigned)hh | ((unsigned)hl << 16);
      unsigned* hc = role ? h2c : h0c;
      __hip_atomic_store(hc + (size_t)(b0 + row) * HID + hid0 + col, pk,
                         __ATOMIC_RELAXED, __HIP_MEMORY_SCOPE_AGENT);
    }

    group_barrier(flags, (unsigned)(s + 1), tid, wid);
  }

  // ---- FC epilogue: WG 0 of each group, 16 rows x 2 outs (h2 final in buf 0) ----
  {
    const int p = tid >> 4, q = tid & 15;   // 32 (row,out) pairs x 16 K-16ths
    float acc = 0.f;
    if (wid == 0 && tid < 512) {
      const int b = b0 + (p >> 1), o = p & 1;
      const unsigned* sp = h2s + (size_t)b * HID + q * 32;
      const float* wf = Wfc + (size_t)o * HID + q * 32;
#pragma unroll 8
      for (int i = 0; i < 32; ++i) {
        unsigned u = ald(sp + i);
        acc += (bf2f((unsigned short)(u & 0xffff)) + bf2f((unsigned short)(u >> 16))) * wf[i];
      }
      glf[p * 16 + q] = acc;
    }
    __syncthreads();
    if (wid == 0 && tid < 512 && q == 0) {
      float t = 0.f;
#pragma unroll
      for (int i = 0; i < 16; ++i) t += glf[p * 16 + i];
      out[(b0 + (p >> 1)) * 2 + (p & 1)] = t + bfc[p & 1];
    }
  }
}

// ---------------------------------------------------------------------------
extern "C" void kernel_launch(void* const* d_in, const int* in_sizes, int n_in,
                              void* d_out, int out_size, void* d_ws, size_t ws_size,
                              hipStream_t stream) {
  const float* x    = (const float*)d_in[0];
  const float* Wih0 = (const float*)d_in[1];
  const float* Whh0 = (const float*)d_in[2];
  const float* bih0 = (const float*)d_in[3];
  const float* bhh0 = (const float*)d_in[4];
  const float* Wih1 = (const float*)d_in[5];
  const float* Whh1 = (const float*)d_in[6];
  const float* bih1 = (const float*)d_in[7];
  const float* bhh1 = (const float*)d_in[8];
  const float* Wfc  = (const float*)d_in[9];
  const float* bfc  = (const float*)d_in[10];
  float* out = (float*)d_out;

  // Workspace layout (~15.7 MB)
  short* W0h = (short*)d_ws;
  short* W0l = W0h + (size_t)G4H * K0;
  short* W1h = W0l + (size_t)G4H * K0;
  short* W1l = W1h + (size_t)G4H * K1;
  unsigned* h0s = (unsigned*)(W1l + (size_t)G4H * K1);   // [2 buf][BATCH][HID] packed
  unsigned* h2s = h0s + (size_t)2 * BATCH * HID;
  unsigned* counters = h2s + (size_t)2 * BATCH * HID;     // 16 groups x 64 dw (flags)
  float* bsum0 = (float*)(counters + 1024);
  float* bsum1 = bsum0 + G4H;

  // Zero h double-buffers + flags (every launch: graph-replay safe)
  (void)hipMemsetAsync(h0s, 0,
                       (size_t)4 * BATCH * HID * sizeof(unsigned) + 1024 * sizeof(unsigned),
                       stream);

  const int total = G4H * K0 + G4H * K1 + 2 * G4H;
  conv_weights<<<(total + 255) / 256, 256, 0, stream>>>(
      Wih0, Whh0, Wih1, Whh1, bih0, bhh0, bih1, bhh1,
      W0h, W0l, W1h, W1l, bsum0, bsum1);

  void* args[] = {(void*)&x,    (void*)&Wfc,  (void*)&bfc,
                  (void*)&W0h,  (void*)&W0l,  (void*)&W1h, (void*)&W1l,
                  (void*)&bsum0, (void*)&bsum1,
                  (void*)&h0s,  (void*)&h2s,  (void*)&counters, (void*)&out};
  (void)hipLaunchCooperativeKernel((void*)lstm_fused, dim3(256), dim3(1024), args, 0,
                                   stream);
}

// Round 13
// 16714.497 us; speedup vs baseline: 1.2261x; 1.2261x over previous
//
#include <hip/hip_runtime.h>

// Problem constants
#define IN_DIM 128
#define HID    512
#define BATCH  256
#define SEQT   512
#define G4H    2048
#define K0     640       // IN_DIM + HID (layer0 concat K)
#define K1     1024      // HID + HID   (layer1 concat K)
#define NC0    20        // K0/32
#define NC1    32        // K1/32
#define ROWB   2048      // bytes per A row (1024 bf16 cols)
#define FSTRIDE 32       // flag stride in dwords = 128B = own cache line per WG

typedef __attribute__((ext_vector_type(8))) short bf16x8;
typedef __attribute__((ext_vector_type(4))) float f32x4;

#define MFMA16 __builtin_amdgcn_mfma_f32_16x16x32_bf16
// glf layout [row 32][gate 4][col 32 +1 pad]
#define GL(r, g, c) ((r) * 132 + (g) * 33 + (c))

__device__ __forceinline__ unsigned short f2bf(float f) {  // RNE float->bf16
  unsigned u = __float_as_uint(f);
  u += 0x7fffu + ((u >> 16) & 1u);
  return (unsigned short)(u >> 16);
}
__device__ __forceinline__ float bf2f(unsigned short s) {
  return __uint_as_float(((unsigned)s) << 16);
}
__device__ __forceinline__ float sigm(float x) { return 1.0f / (1.0f + __expf(-x)); }
__device__ __forceinline__ float tanh_f(float x) {
  float xc = fminf(fmaxf(x, -15.0f), 15.0f);
  float e = __expf(2.0f * xc);
  return (e - 1.0f) / (e + 1.0f);
}

// MALL-coherent dword load (agent scope)
__device__ __forceinline__ unsigned ald(const unsigned* p) {
  return __hip_atomic_load(p, __ATOMIC_RELAXED, __HIP_MEMORY_SCOPE_AGENT);
}

// ---------------------------------------------------------------------------
// Prep: packed hi/lo bf16 weight tiles + bias sums (layout unchanged).
// Tile t = slice16*4+gate; within tile: [kchunk][lane(col=l&15, ko=(l>>4)*8)][8].
// ---------------------------------------------------------------------------
__global__ void conv_weights(const float* __restrict__ Wih0, const float* __restrict__ Whh0,
                             const float* __restrict__ Wih1, const float* __restrict__ Whh1,
                             const float* __restrict__ bih0, const float* __restrict__ bhh0,
                             const float* __restrict__ bih1, const float* __restrict__ bhh1,
                             short* __restrict__ W0h, short* __restrict__ W0l,
                             short* __restrict__ W1h, short* __restrict__ W1l,
                             float* __restrict__ bsum0, float* __restrict__ bsum1) {
  int idx = blockIdx.x * blockDim.x + threadIdx.x;
  const int N0 = G4H * K0, N1 = G4H * K1;
  if (idx < N0) {
    int tile = idx / (K0 * 16), rem = idx % (K0 * 16);
    int kcg = rem >> 9, l = (rem >> 3) & 63, j = rem & 7;
    int slice = tile >> 2, g = tile & 3;
    int c = l & 15, k = kcg * 32 + ((l >> 4) << 3) + j;
    int n = g * HID + slice * 16 + c;
    float w = (k < IN_DIM) ? Wih0[n * IN_DIM + k] : Whh0[n * HID + (k - IN_DIM)];
    unsigned short hi = f2bf(w);
    W0h[idx] = (short)hi;
    W0l[idx] = (short)f2bf(w - bf2f(hi));
  } else if (idx < N0 + N1) {
    int d = idx - N0;
    int tile = d / (K1 * 16), rem = d % (K1 * 16);
    int kcg = rem >> 9, l = (rem >> 3) & 63, j = rem & 7;
    int slice = tile >> 2, g = tile & 3;
    int c = l & 15, k = kcg * 32 + ((l >> 4) << 3) + j;
    int n = g * HID + slice * 16 + c;
    float w = (k < HID) ? Wih1[n * HID + k] : Whh1[n * HID + (k - HID)];
    unsigned short hi = f2bf(w);
    W1h[d] = (short)hi;
    W1l[d] = (short)f2bf(w - bf2f(hi));
  } else if (idx < N0 + N1 + G4H) {
    int n = idx - (N0 + N1);
    bsum0[n] = bih0[n] + bhh0[n];
  } else if (idx < N0 + N1 + 2 * G4H) {
    int n = idx - (N0 + N1 + G4H);
    bsum1[n] = bih1[n] + bhh1[n];
  }
}

// ---------------------------------------------------------------------------
// Staging: packed h planes (dword = hi|lo<<16) -> swizzled hi/lo LDS planes.
// Batched MALL-coherent dwordx4 loads, ONE vmcnt window per call.
// ---------------------------------------------------------------------------
#define PKH(a, b) ((unsigned)((a) & 0xffffu) | (((b) & 0xffffu) << 16))
#define PKL(a, b) (((a) >> 16) | ((b) & 0xffff0000u))

__device__ __forceinline__ void unpack16(char* bh, char* bl, int byte0, int rx,
                                         const uint4& v0, const uint4& v1,
                                         const uint4& v2, const uint4& v3) {
  int4 h0 = {(int)PKH(v0.x, v0.y), (int)PKH(v0.z, v0.w), (int)PKH(v1.x, v1.y), (int)PKH(v1.z, v1.w)};
  int4 h1 = {(int)PKH(v2.x, v2.y), (int)PKH(v2.z, v2.w), (int)PKH(v3.x, v3.y), (int)PKH(v3.z, v3.w)};
  int4 l0 = {(int)PKL(v0.x, v0.y), (int)PKL(v0.z, v0.w), (int)PKL(v1.x, v1.y), (int)PKL(v1.z, v1.w)};
  int4 l1 = {(int)PKL(v2.x, v2.y), (int)PKL(v2.z, v2.w), (int)PKL(v3.x, v3.y), (int)PKL(v3.z, v3.w)};
  *(int4*)(bh + (byte0 ^ rx)) = h0;
  *(int4*)(bh + ((byte0 + 16) ^ rx)) = h1;
  *(int4*)(bl + (byte0 ^ rx)) = l0;
  *(int4*)(bl + ((byte0 + 16) ^ rx)) = l1;
}

// one plane (L0: h0p -> elems [128,640))
__device__ __forceinline__ void stage_one(char* AhiB, char* AloB,
                                          const unsigned* __restrict__ plane,
                                          int b0, int colOff, int tid) {
  const int row = tid >> 5, c32 = tid & 31;
  const unsigned* p = plane + (size_t)(b0 + row) * HID + c32 * 16;
  uint4 v0, v1, v2, v3;
  asm volatile(
      "global_load_dwordx4 %0, %4, off sc0 sc1\n\t"
      "global_load_dwordx4 %1, %4, off offset:16 sc0 sc1\n\t"
      "global_load_dwordx4 %2, %4, off offset:32 sc0 sc1\n\t"
      "global_load_dwordx4 %3, %4, off offset:48 sc0 sc1\n\t"
      "s_waitcnt vmcnt(0)"
      : "=&v"(v0), "=&v"(v1), "=&v"(v2), "=&v"(v3)
      : "v"(p)
      : "memory");
  const int rx = (row & 7) << 4;
  unpack16(AhiB + row * ROWB, AloB + row * ROWB, (colOff + c32 * 16) * 2, rx, v0, v1, v2, v3);
}

// two planes (L1: h0p -> [0,512), h2p -> [512,1024))
__device__ __forceinline__ void stage_two(char* AhiB, char* AloB,
                                          const unsigned* __restrict__ pA,
                                          const unsigned* __restrict__ pB,
                                          int b0, int tid) {
  const int row = tid >> 5, c32 = tid & 31;
  const unsigned* p0 = pA + (size_t)(b0 + row) * HID + c32 * 16;
  const unsigned* p2 = pB + (size_t)(b0 + row) * HID + c32 * 16;
  uint4 v0, v1, v2, v3, w0, w1, w2, w3;
  asm volatile(
      "global_load_dwordx4 %0, %8, off sc0 sc1\n\t"
      "global_load_dwordx4 %1, %8, off offset:16 sc0 sc1\n\t"
      "global_load_dwordx4 %2, %8, off offset:32 sc0 sc1\n\t"
      "global_load_dwordx4 %3, %8, off offset:48 sc0 sc1\n\t"
      "global_load_dwordx4 %4, %9, off sc0 sc1\n\t"
      "global_load_dwordx4 %5, %9, off offset:16 sc0 sc1\n\t"
      "global_load_dwordx4 %6, %9, off offset:32 sc0 sc1\n\t"
      "global_load_dwordx4 %7, %9, off offset:48 sc0 sc1\n\t"
      "s_waitcnt vmcnt(0)"
      : "=&v"(v0), "=&v"(v1), "=&v"(v2), "=&v"(v3),
        "=&v"(w0), "=&v"(w1), "=&v"(w2), "=&v"(w3)
      : "v"(p0), "v"(p2)
      : "memory");
  const int rx = (row & 7) << 4;
  char* bh = AhiB + row * ROWB;
  char* bl = AloB + row * ROWB;
  unpack16(bh, bl, (c32 * 16) * 2, rx, v0, v1, v2, v3);
  unpack16(bh, bl, (HID + c32 * 16) * 2, rx, w0, w1, w2, w3);
}
#undef PKH
#undef PKL

// ---------------------------------------------------------------------------
// Per-wave GEMM: 32 rows x 32 cols (2 N-tiles) over NKC k-chunks.
// Split precision: hi*hi + hi*lo + lo*hi  (12 MFMA / chunk).
// ---------------------------------------------------------------------------
template <int NKC>
__device__ __forceinline__ void gemm32(const char* Ah, const char* Al,
                                       const short* __restrict__ Bh0, const short* __restrict__ Bl0,
                                       const short* __restrict__ Bh1, const short* __restrict__ Bl1,
                                       int lane, int aoff,
                                       f32x4& a00, f32x4& a01, f32x4& a10, f32x4& a11) {
  const int row = lane & 15;
  const int ko  = (lane >> 4) * 8;
  const int rx  = (row & 7) << 4;
  const char* pAh0 = Ah + row * ROWB;
  const char* pAh1 = Ah + (row + 16) * ROWB;
  const char* pAl0 = Al + row * ROWB;
  const char* pAl1 = Al + (row + 16) * ROWB;
#pragma unroll
  for (int kc = 0; kc < NKC; ++kc) {
    const int off = ((aoff + kc * 32 + ko) * 2) ^ rx;
    bf16x8 ah0 = *(const bf16x8*)(pAh0 + off);
    bf16x8 ah1 = *(const bf16x8*)(pAh1 + off);
    bf16x8 al0 = *(const bf16x8*)(pAl0 + off);
    bf16x8 al1 = *(const bf16x8*)(pAl1 + off);
    bf16x8 bh0 = *(const bf16x8*)(Bh0 + kc * 512 + lane * 8);
    bf16x8 bl0 = *(const bf16x8*)(Bl0 + kc * 512 + lane * 8);
    bf16x8 bh1 = *(const bf16x8*)(Bh1 + kc * 512 + lane * 8);
    bf16x8 bl1 = *(const bf16x8*)(Bl1 + kc * 512 + lane * 8);
    a00 = MFMA16(ah0, bh0, a00, 0, 0, 0);
    a01 = MFMA16(ah1, bh0, a01, 0, 0, 0);
    a00 = MFMA16(ah0, bl0, a00, 0, 0, 0);
    a01 = MFMA16(ah1, bl0, a01, 0, 0, 0);
    a00 = MFMA16(al0, bh0, a00, 0, 0, 0);
    a01 = MFMA16(al1, bh0, a01, 0, 0, 0);
    a10 = MFMA16(ah0, bh1, a10, 0, 0, 0);
    a11 = MFMA16(ah1, bh1, a11, 0, 0, 0);
    a10 = MFMA16(ah0, bl1, a10, 0, 0, 0);
    a11 = MFMA16(ah1, bl1, a11, 0, 0, 0);
    a10 = MFMA16(al0, bh1, a10, 0, 0, 0);
    a11 = MFMA16(al1, bh1, a11, 0, 0, 0);
  }
}

__device__ __forceinline__ void finq32(float* glf, int g, int lane,
                                       const f32x4& a00, const f32x4& a01,
                                       const f32x4& a10, const f32x4& a11) {
  // C/D layout: col = lane&15, row = (lane>>4)*4 + reg  [measured m89]
  const int col = lane & 15;
  const int r0  = (lane >> 4) * 4;
#pragma unroll
  for (int r = 0; r < 4; ++r) {
    atomicAdd(glf + GL(r0 + r, g, col), a00[r]);       // ds_add_f32
    atomicAdd(glf + GL(16 + r0 + r, g, col), a01[r]);
    atomicAdd(glf + GL(r0 + r, g, col + 16), a10[r]);
    atomicAdd(glf + GL(16 + r0 + r, g, col + 16), a11[r]);
  }
}

// ---------------------------------------------------------------------------
// Flag-array group barrier, ONE 128B LINE PER WG (the R13 change).
// R3-R9 put all 32 arrival stores in a single MALL line (counter, or flags
// 4B apart) -> ~32 serialized line-exclusive operations ~= the 31us/step
// invariant. With flags 128B apart, arrival stores pipeline in parallel;
// the poll is one 32-lane gather across 32 distinct lines.
// ---------------------------------------------------------------------------
__device__ __forceinline__ void group_barrier(unsigned* flags, unsigned target,
                                              int tid, int wid) {
  asm volatile("s_waitcnt vmcnt(0)" ::: "memory");   // all this thread's stores acked
  __syncthreads();                                   // whole WG arrived
  if (tid < 64) {
    if (tid == 0)
      __hip_atomic_store(flags + wid * FSTRIDE, target,
                         __ATOMIC_RELAXED, __HIP_MEMORY_SCOPE_AGENT);
    const int i = (tid & 31) * FSTRIDE;
    while (true) {
      unsigned v = ald(flags + i);
      if (__all((int)(v >= target))) break;
      __builtin_amdgcn_s_sleep(1);
    }
  }
  __syncthreads();
}

// ---------------------------------------------------------------------------
// Persistent fused 2-layer LSTM, layer-split across WGs (R9 structure).
// 256 WGs x 1024 thr. grp = blk>>5 (32 batch rows). Within a group:
//   WGs 0-15  = layer 0, 32 hid cols each (reads x_t + h0p, writes h0c)
//   WGs 16-31 = layer 1, one step behind  (reads h0p + h2p, writes h2c)
// Wave w: gate g = w&3, K-quarter kq = w>>2; gate partials via LDS atomicAdd.
// Per step: stage -> sync -> gemm -> sync -> update+store -> flag barrier.
// ---------------------------------------------------------------------------
__global__ void __launch_bounds__(1024, 4) lstm_fused(
    const float* __restrict__ x,
    const float* __restrict__ Wfc, const float* __restrict__ bfc,
    const short* __restrict__ W0h, const short* __restrict__ W0l,
    const short* __restrict__ W1h, const short* __restrict__ W1l,
    const float* __restrict__ bsum0, const float* __restrict__ bsum1,
    unsigned* __restrict__ h0s, unsigned* __restrict__ h2s,
    unsigned* __restrict__ counters,
    float* __restrict__ out) {
  const int tid  = threadIdx.x;
  const int wv   = tid >> 6;
  const int lane = tid & 63;
  const int wid  = blockIdx.x & 31;
  const int grp  = blockIdx.x >> 5;
  const int role = wid >> 4;           // 0 = layer0, 1 = layer1
  const int w16  = wid & 15;           // 16 col-slices of 32
  const int hid0 = w16 * 32;
  const int b0   = grp * 32;
  unsigned* flags = counters + grp * (32 * FSTRIDE);   // 4KB per group

  __shared__ __align__(16) char AhiB[32 * ROWB];   // 65536 B
  __shared__ __align__(16) char AloB[32 * ROWB];   // 65536 B
  __shared__ float glf[32 * 132];                   // 16896 B gate exchange / FC scratch

  const int g  = wv & 3;
  const int kq = wv >> 2;
  // Weight tile pointers: 16-col tiles t0,t1 for this wave's 32 cols.
  const int t0 = (w16 * 2) * 4 + g, t1 = t0 + 4;
  const short *Bh0, *Bl0, *Bh1, *Bl1;
  int aoff;
  if (role == 0) {
    Bh0 = W0h + ((size_t)t0 * NC0 + (size_t)kq * 5) * 512;
    Bl0 = W0l + ((size_t)t0 * NC0 + (size_t)kq * 5) * 512;
    Bh1 = W0h + ((size_t)t1 * NC0 + (size_t)kq * 5) * 512;
    Bl1 = W0l + ((size_t)t1 * NC0 + (size_t)kq * 5) * 512;
    aoff = kq * 160;
  } else {
    Bh0 = W1h + ((size_t)t0 * NC1 + (size_t)kq * 8) * 512;
    Bl0 = W1l + ((size_t)t0 * NC1 + (size_t)kq * 8) * 512;
    Bh1 = W1h + ((size_t)t1 * NC1 + (size_t)kq * 8) * 512;
    Bl1 = W1l + ((size_t)t1 * NC1 + (size_t)kq * 8) * 512;
    aoff = kq * 256;
  }

  // Cell state + biases: 1 output/thread (row = tid>>5, col = tid&31)
  float c = 0.f;
  float bs[4];
  {
    const int n = hid0 + (tid & 31);
    const float* bsp = role ? bsum1 : bsum0;
#pragma unroll
    for (int q = 0; q < 4; ++q) bs[q] = bsp[q * HID + n];
  }
  for (int i = tid; i < 32 * 132; i += 1024) glf[i] = 0.f;

  const size_t PL = (size_t)BATCH * HID;

  for (int s = 0; s <= SEQT; ++s) {
    const int cur = s & 1, prv = cur ^ 1;
    unsigned* h0c = h0s + (size_t)cur * PL;
    const unsigned* h0p = h0s + (size_t)prv * PL;
    unsigned* h2c = h2s + (size_t)cur * PL;
    const unsigned* h2p = h2s + (size_t)prv * PL;
    const bool active = role ? (s > 0) : (s < SEQT);

    // ---- stage ----
    if (active) {
      if (role == 0) {
        {  // x_t -> elems [0,128) hi/lo (plain cached loads)
          const int row = tid >> 5, t32 = tid & 31;
          const int rx = (row & 7) << 4;
          const float* xs = x + ((size_t)(b0 + row) * SEQT + s) * IN_DIM + t32 * 4;
          float4 xv = *(const float4*)xs;
          unsigned short h0v = f2bf(xv.x), h1v = f2bf(xv.y), h2v = f2bf(xv.z), h3v = f2bf(xv.w);
          uint2 hd = {(unsigned)h0v | ((unsigned)h1v << 16), (unsigned)h2v | ((unsigned)h3v << 16)};
          uint2 ld = {(unsigned)f2bf(xv.x - bf2f(h0v)) | ((unsigned)f2bf(xv.y - bf2f(h1v)) << 16),
                      (unsigned)f2bf(xv.z - bf2f(h2v)) | ((unsigned)f2bf(xv.w - bf2f(h3v)) << 16)};
          const int byte = (t32 * 8) ^ rx;
          *(uint2*)(AhiB + row * ROWB + byte) = hd;
          *(uint2*)(AloB + row * ROWB + byte) = ld;
        }
        stage_one(AhiB, AloB, h0p, b0, IN_DIM, tid);     // h0p -> [128,640)
      } else {
        stage_two(AhiB, AloB, h0p, h2p, b0, tid);        // h0p->[0,512), h2p->[512,1024)
      }
    }
    __syncthreads();

    // ---- gemm + gate reduce ----
    if (active) {
      f32x4 a00 = {0.f, 0.f, 0.f, 0.f}, a01 = {0.f, 0.f, 0.f, 0.f};
      f32x4 a10 = {0.f, 0.f, 0.f, 0.f}, a11 = {0.f, 0.f, 0.f, 0.f};
      if (role == 0)
        gemm32<5>(AhiB, AloB, Bh0, Bl0, Bh1, Bl1, lane, aoff, a00, a01, a10, a11);
      else
        gemm32<8>(AhiB, AloB, Bh0, Bl0, Bh1, Bl1, lane, aoff, a00, a01, a10, a11);
      finq32(glf, g, lane, a00, a01, a10, a11);
    }
    __syncthreads();

    // ---- update + coherent h store ----
    if (active) {
      const int row = tid >> 5, col = tid & 31;
      float gi = glf[GL(row, 0, col)] + bs[0];
      float gf = glf[GL(row, 1, col)] + bs[1];
      float gg = glf[GL(row, 2, col)] + bs[2];
      float go = glf[GL(row, 3, col)] + bs[3];
      glf[GL(row, 0, col)] = 0.f; glf[GL(row, 1, col)] = 0.f;
      glf[GL(row, 2, col)] = 0.f; glf[GL(row, 3, col)] = 0.f;
      float i = sigm(gi), f = sigm(gf), gv = tanh_f(gg), o = sigm(go);
      float cc = f * c + i * gv;
      c = cc;
      float h = o * tanh_f(cc);
      unsigned short hh = f2bf(h);
      unsigned short hl = f2bf(h - bf2f(hh));
      unsigned pk = (unsigned)hh | ((unsigned)hl << 16);
      unsigned* hc = role ? h2c : h0c;
      __hip_atomic_store(hc + (size_t)(b0 + row) * HID + hid0 + col, pk,
                         __ATOMIC_RELAXED, __HIP_MEMORY_SCOPE_AGENT);
    }

    group_barrier(flags, (unsigned)(s + 1), tid, wid);
  }

  // ---- FC epilogue: WG 0 of each group (h2 final in buf 0) ----
  {
    const int p = tid >> 3, q = tid & 7;   // 64 (row,out) pairs x 8 K-eighths
    float acc = 0.f;
    if (wid == 0 && tid < 512) {
      const int b = b0 + (p >> 1), o = p & 1;
      const unsigned* sp = h2s + (size_t)b * HID + q * 64;
      const float* wf = Wfc + (size_t)o * HID + q * 64;
#pragma unroll 8
      for (int i = 0; i < 64; ++i) {
        unsigned u = ald(sp + i);
        acc += (bf2f((unsigned short)(u & 0xffff)) + bf2f((unsigned short)(u >> 16))) * wf[i];
      }
      glf[p * 8 + q] = acc;
    }
    __syncthreads();
    if (wid == 0 && tid < 512 && q == 0) {
      float t = 0.f;
#pragma unroll
      for (int i = 0; i < 8; ++i) t += glf[p * 8 + i];
      out[(b0 + (p >> 1)) * 2 + (p & 1)] = t + bfc[p & 1];
    }
  }
}

// ---------------------------------------------------------------------------
extern "C" void kernel_launch(void* const* d_in, const int* in_sizes, int n_in,
                              void* d_out, int out_size, void* d_ws, size_t ws_size,
                              hipStream_t stream) {
  const float* x    = (const float*)d_in[0];
  const float* Wih0 = (const float*)d_in[1];
  const float* Whh0 = (const float*)d_in[2];
  const float* bih0 = (const float*)d_in[3];
  const float* bhh0 = (const float*)d_in[4];
  const float* Wih1 = (const float*)d_in[5];
  const float* Whh1 = (const float*)d_in[6];
  const float* bih1 = (const float*)d_in[7];
  const float* bhh1 = (const float*)d_in[8];
  const float* Wfc  = (const float*)d_in[9];
  const float* bfc  = (const float*)d_in[10];
  float* out = (float*)d_out;

  // Workspace layout (~15.8 MB)
  short* W0h = (short*)d_ws;
  short* W0l = W0h + (size_t)G4H * K0;
  short* W1h = W0l + (size_t)G4H * K0;
  short* W1l = W1h + (size_t)G4H * K1;
  unsigned* h0s = (unsigned*)(W1l + (size_t)G4H * K1);   // [2 buf][BATCH][HID] packed
  unsigned* h2s = h0s + (size_t)2 * BATCH * HID;
  unsigned* counters = h2s + (size_t)2 * BATCH * HID;     // 8 groups x 32 x FSTRIDE dw
  float* bsum0 = (float*)(counters + 8 * 32 * FSTRIDE);
  float* bsum1 = bsum0 + G4H;

  // Zero h double-buffers + padded flags (every launch: graph-replay safe)
  (void)hipMemsetAsync(h0s, 0,
                       (size_t)4 * BATCH * HID * sizeof(unsigned) +
                           (size_t)8 * 32 * FSTRIDE * sizeof(unsigned),
                       stream);

  const int total = G4H * K0 + G4H * K1 + 2 * G4H;
  conv_weights<<<(total + 255) / 256, 256, 0, stream>>>(
      Wih0, Whh0, Wih1, Whh1, bih0, bhh0, bih1, bhh1,
      W0h, W0l, W1h, W1l, bsum0, bsum1);

  void* args[] = {(void*)&x,    (void*)&Wfc,  (void*)&bfc,
                  (void*)&W0h,  (void*)&W0l,  (void*)&W1h, (void*)&W1l,
                  (void*)&bsum0, (void*)&bsum1,
                  (void*)&h0s,  (void*)&h2s,  (void*)&counters, (void*)&out};
  (void)hipLaunchCooperativeKernel((void*)lstm_fused, dim3(256), dim3(1024), args, 0,
                                   stream);
}